// Round 3
// baseline (107.090 us; speedup 1.0000x reference)
//
#include <hip/hip_runtime.h>
#include <stdint.h>

// Problem constants
#define N_ANCHOR 2048
#define DIM 128
#define NEG_PER 15
#define NZ 32768                    // 2048*16 candidate rows
#define NROWS (N_ANCHOR + NZ)       // 34816
#define INV_TEMP 3.3333333333333335f
#define LOG2E 1.4426950408889634f
#define LN2 0.6931471805599453f
#define TOTAL_ELEMS 67108864.0f
#define A_PRESCALE (INV_TEMP * LOG2E)   // folded into anchor normalization
#define NBLK 512                    // gemm grid = 16 rb x 32 cg
#define NTILE 8                     // 128-col tiles per block

using bf16x8 = __attribute__((ext_vector_type(8))) __bf16;
using f32x4  = __attribute__((ext_vector_type(4))) float;

// ---------- helpers ----------
static __device__ __forceinline__ unsigned short f2bf(float f) {
  union { float f; unsigned u; } v; v.f = f;
  unsigned r = v.u + 0x7FFF + ((v.u >> 16) & 1);   // round-to-nearest-even
  return (unsigned short)(r >> 16);
}

static __device__ __forceinline__ void gload_lds16(const void* g, void* l) {
  __builtin_amdgcn_global_load_lds(
      (const __attribute__((address_space(1))) void*)g,
      (__attribute__((address_space(3))) void*)l, 16, 0, 0);
}

// ---------- kernel 1: L2-normalize rows, cast to bf16 ----------
// 32 lanes per row, float4 loads. Anchor rows pre-scaled by INV_TEMP*LOG2E.
__global__ __launch_bounds__(256) void norm_kernel(
    const float* __restrict__ anchor, const float* __restrict__ pos,
    const float* __restrict__ neg, unsigned short* __restrict__ a_bf,
    unsigned short* __restrict__ z_bf) {
  int row = blockIdx.x * 8 + (threadIdx.x >> 5);
  int l32 = threadIdx.x & 31;
  const float* src;
  unsigned short* dst;
  float pre;
  if (row < N_ANCHOR) {
    src = anchor + row * DIM;
    dst = a_bf + row * DIM;
    pre = A_PRESCALE;
  } else {
    int rz = row - N_ANCHOR;
    int j = rz >> 4, k = rz & 15;
    src = (k == 0) ? (pos + j * DIM) : (neg + (j * NEG_PER + (k - 1)) * DIM);
    dst = z_bf + rz * DIM;
    pre = 1.0f;
  }
  float4 v = ((const float4*)src)[l32];
  float s = v.x * v.x + v.y * v.y + v.z * v.z + v.w * v.w;
  #pragma unroll
  for (int o = 16; o >= 1; o >>= 1) s += __shfl_xor(s, o, 32);
  float scale = pre / fmaxf(sqrtf(s), 1e-12f);
  ushort4 o4;
  o4.x = f2bf(v.x * scale); o4.y = f2bf(v.y * scale);
  o4.z = f2bf(v.z * scale); o4.w = f2bf(v.w * scale);
  ((ushort4*)dst)[l32] = o4;
}

// ---------- kernel 2: fused GEMM + loss, multi-tile pipelined ----------
// A stripe (128 rows x K=128) in REGISTERS (loaded once, L2-hot).
// B double-buffered in LDS (2x32KB), fragment order (ds_read = base+lane*16).
// Counted vmcnt(8) + raw s_barrier: next tile's 8 global_load_lds stay in
// flight across the barrier (T3/T4 pattern, never drain to 0 mid-loop).
__global__ __launch_bounds__(256, 2) void gemm_loss_kernel(
    const unsigned short* __restrict__ a_bf,
    const unsigned short* __restrict__ z_bf,
    float* __restrict__ partial, unsigned* __restrict__ counter,
    float* __restrict__ out) {
  __shared__ __align__(16) unsigned short Bs[2][128 * DIM];  // 64 KB
  __shared__ float red[4];
  __shared__ int lastflag;

  const int t    = threadIdx.x;
  const int bid  = blockIdx.x;
  const int rb   = bid >> 5;     // 16 row-blocks (A stripe)
  const int cg   = bid & 31;     // 32 col-groups x 8 tiles
  const int wave = t >> 6;
  const int lane = t & 63;
  const int wr   = wave >> 1, wc = wave & 1;
  const int g    = lane >> 4;
  const int r16  = lane & 15;

  // B staging source permutation (fragment order; verified R2):
  // slot it*256+wave*64+lane <- B[it*16 + r16][chunk wave*4 + (lane>>4)]
  const int src_off = r16 * DIM + (wave * 4 + (lane >> 4)) * 8;  // shorts
  const unsigned short* Bg0 = z_bf + (cg * NTILE) * 128 * DIM;

#define STAGE_B(buf, tile)                                              \
  {                                                                     \
    const unsigned short* bg = Bg0 + (tile) * 128 * DIM + src_off;      \
    _Pragma("unroll")                                                   \
    for (int it = 0; it < 8; ++it)                                      \
      gload_lds16(bg + it * 16 * DIM, (buf) + (it * 256 + wave * 64) * 8); \
  }

  STAGE_B(Bs[0], 0)

  // A fragments -> registers: af[i][ks] = A[rb*128+wr*64+i*16+r16][(ks*4+g)*8..+8]
  bf16x8 af[4][4];
  {
    const unsigned short* Arow =
        a_bf + (rb * 128 + wr * 64 + r16) * DIM + g * 8;
    #pragma unroll
    for (int i = 0; i < 4; ++i)
      #pragma unroll
      for (int ks = 0; ks < 4; ++ks)
        af[i][ks] = *(const bf16x8*)(Arow + i * 16 * DIM + ks * 32);
  }

  STAGE_B(Bs[1], 1)

  float sumt = 0.f, sumab = 0.f, logacc = 0.f, diagsum = 0.f;

  #pragma unroll
  for (int tt = 0; tt < NTILE; ++tt) {
    // wait: my 8 loads for tile tt done; tile tt+1's 8 stay in flight
    if (tt < NTILE - 1) asm volatile("s_waitcnt vmcnt(8)" ::: "memory");
    else                asm volatile("s_waitcnt vmcnt(0)" ::: "memory");
    __builtin_amdgcn_s_barrier();
    asm volatile("" ::: "memory");

    const unsigned short* Bbase = Bs[tt & 1] + wc * 8192 + lane * 8;

    f32x4 acc[4][4];
    #pragma unroll
    for (int i = 0; i < 4; ++i)
      #pragma unroll
      for (int j = 0; j < 4; ++j) acc[i][j] = 0.0f;

    #pragma unroll
    for (int ks = 0; ks < 4; ++ks) {
      bf16x8 bfr[4];
      #pragma unroll
      for (int f = 0; f < 4; ++f)
        bfr[f] = *(const bf16x8*)(Bbase + ks * 512 + f * 2048);
      #pragma unroll
      for (int i = 0; i < 4; ++i)
        #pragma unroll
        for (int j = 0; j < 4; ++j)
          acc[i][j] = __builtin_amdgcn_mfma_f32_16x16x32_bf16(
              af[i][ks], bfr[j], acc[i][j], 0, 0, 0);
    }

    // per-tile epilogue: 3 VALU + 1 trans per element, 4-way dep chains
    float st[4] = {0.f, 0.f, 0.f, 0.f};
    float sab[4] = {0.f, 0.f, 0.f, 0.f};
    float pr[4] = {1.f, 1.f, 1.f, 1.f};
    #pragma unroll
    for (int i = 0; i < 4; ++i)
      #pragma unroll
      for (int j = 0; j < 4; ++j)
        #pragma unroll
        for (int r = 0; r < 4; ++r) {
          float tv = acc[i][j][r];
          st[r]  += tv;
          sab[r] += fabsf(tv);
          pr[r] = fmaf(pr[r], __builtin_amdgcn_exp2f(-fabsf(tv)), pr[r]);
        }
    sumt  += (st[0] + st[1]) + (st[2] + st[3]);
    sumab += (sab[0] + sab[1]) + (sab[2] + sab[3]);
    // 64 factors in [1,2] -> product <= 2^64, safe; one log2 per tile
    logacc += __builtin_amdgcn_logf((pr[0] * pr[1]) * (pr[2] * pr[3]));

    // diagonal fixup (only blocks whose tiles hit the diagonal: cg in {2rb,2rb+1})
    const int ct = cg * NTILE + tt;
    if ((ct >> 4) == rb) {
      const int obase = ct * 8 + wc * 4;
      const int rbase = rb * 128 + wr * 64 + g * 4;
      float sd = 0.f;
      #pragma unroll
      for (int i = 0; i < 4; ++i)
        #pragma unroll
        for (int r = 0; r < 4; ++r) {
          int gi = rbase + i * 16 + r;
          #pragma unroll
          for (int j = 0; j < 4; ++j)
            sd += (gi == obase + j) ? acc[i][j][r] : 0.f;
        }
      diagsum += sd;
    }

    asm volatile("" ::: "memory");
    __builtin_amdgcn_s_barrier();   // all waves done reading Bs[tt&1]
    if (tt + 2 < NTILE) STAGE_B(Bs[tt & 1], tt + 2)
  }

  float local = 0.5f * (sumt + sumab) + logacc - diagsum;
  #pragma unroll
  for (int o = 32; o >= 1; o >>= 1) local += __shfl_xor(local, o);
  if (lane == 0) red[wave] = local;
  __syncthreads();

  if (t == 0) {
    float bsum = (red[0] + red[1]) + (red[2] + red[3]);
    __hip_atomic_store(&partial[bid], bsum, __ATOMIC_RELEASE,
                       __HIP_MEMORY_SCOPE_AGENT);
    unsigned prev = __hip_atomic_fetch_add(counter, 1u, __ATOMIC_ACQ_REL,
                                           __HIP_MEMORY_SCOPE_AGENT);
    lastflag = (prev == NBLK - 1);
  }
  __syncthreads();

  if (lastflag) {   // last block: deterministic fixed-order final reduction
    float s = 0.f;
    for (int i = t; i < NBLK; i += 256)
      s += __hip_atomic_load(&partial[i], __ATOMIC_RELAXED,
                             __HIP_MEMORY_SCOPE_AGENT);
    #pragma unroll
    for (int o = 32; o >= 1; o >>= 1) s += __shfl_xor(s, o);
    if (lane == 0) red[wave] = s;
    __syncthreads();
    if (t == 0)
      out[0] = ((red[0] + red[1]) + (red[2] + red[3])) * (LN2 / TOTAL_ELEMS);
  }
}

extern "C" void kernel_launch(void* const* d_in, const int* in_sizes, int n_in,
                              void* d_out, int out_size, void* d_ws, size_t ws_size,
                              hipStream_t stream) {
  const float* anchor = (const float*)d_in[0];
  const float* pos    = (const float*)d_in[1];
  const float* neg    = (const float*)d_in[2];
  char* ws = (char*)d_ws;
  unsigned short* a_bf = (unsigned short*)ws;                    // 512 KB
  unsigned short* z_bf = (unsigned short*)(ws + 524288);         // 8 MB
  float* partial       = (float*)(ws + 524288 + 8388608);        // 2 KB
  unsigned* counter    = (unsigned*)(ws + 524288 + 8388608 + 2048);

  hipMemsetAsync(counter, 0, sizeof(unsigned), stream);
  norm_kernel<<<dim3(NROWS / 8), dim3(256), 0, stream>>>(
      anchor, pos, neg, a_bf, z_bf);
  gemm_loss_kernel<<<dim3(NBLK), dim3(256), 0, stream>>>(
      a_bf, z_bf, partial, counter, (float*)d_out);
}

// Round 4
// 90.184 us; speedup vs baseline: 1.1875x; 1.1875x over previous
//
#include <hip/hip_runtime.h>
#include <stdint.h>

// Problem constants
#define N_ANCHOR 2048
#define DIM 128
#define NEG_PER 15
#define NZ 32768                    // 2048*16 candidate rows
#define NROWS (N_ANCHOR + NZ)       // 34816
#define INV_TEMP 3.3333333333333335f
#define LOG2E 1.4426950408889634f
#define LN2 0.6931471805599453f
#define TOTAL_ELEMS 67108864.0f
#define A_PRESCALE (INV_TEMP * LOG2E)   // folded into anchor normalization
#define NBLK 512                    // gemm grid = 16 rb x 32 cg
#define NTILE 8                     // 128-col tiles per block

using bf16x8 = __attribute__((ext_vector_type(8))) __bf16;
using f32x4  = __attribute__((ext_vector_type(4))) float;

// ---------- helpers ----------
static __device__ __forceinline__ unsigned short f2bf(float f) {
  union { float f; unsigned u; } v; v.f = f;
  unsigned r = v.u + 0x7FFF + ((v.u >> 16) & 1);   // round-to-nearest-even
  return (unsigned short)(r >> 16);
}

static __device__ __forceinline__ void gload_lds16(const void* g, void* l) {
  __builtin_amdgcn_global_load_lds(
      (const __attribute__((address_space(1))) void*)g,
      (__attribute__((address_space(3))) void*)l, 16, 0, 0);
}

// ---------- kernel 1: L2-normalize rows, cast to bf16 ----------
// 32 lanes per row, float4 loads. Anchor rows pre-scaled by INV_TEMP*LOG2E.
__global__ __launch_bounds__(256) void norm_kernel(
    const float* __restrict__ anchor, const float* __restrict__ pos,
    const float* __restrict__ neg, unsigned short* __restrict__ a_bf,
    unsigned short* __restrict__ z_bf) {
  int row = blockIdx.x * 8 + (threadIdx.x >> 5);
  int l32 = threadIdx.x & 31;
  const float* src;
  unsigned short* dst;
  float pre;
  if (row < N_ANCHOR) {
    src = anchor + row * DIM;
    dst = a_bf + row * DIM;
    pre = A_PRESCALE;
  } else {
    int rz = row - N_ANCHOR;
    int j = rz >> 4, k = rz & 15;
    src = (k == 0) ? (pos + j * DIM) : (neg + (j * NEG_PER + (k - 1)) * DIM);
    dst = z_bf + rz * DIM;
    pre = 1.0f;
  }
  float4 v = ((const float4*)src)[l32];
  float s = v.x * v.x + v.y * v.y + v.z * v.z + v.w * v.w;
  #pragma unroll
  for (int o = 16; o >= 1; o >>= 1) s += __shfl_xor(s, o, 32);
  float scale = pre / fmaxf(sqrtf(s), 1e-12f);
  ushort4 o4;
  o4.x = f2bf(v.x * scale); o4.y = f2bf(v.y * scale);
  o4.z = f2bf(v.z * scale); o4.w = f2bf(v.w * scale);
  ((ushort4*)dst)[l32] = o4;
}

// ---------- kernel 2: fused GEMM + loss, multi-tile pipelined ----------
// A stripe (128 rows x K=128) in REGISTERS (loaded once, L2-hot).
// B double-buffered in LDS (2x32KB), fragment order (ds_read = base+lane*16).
// Counted vmcnt(8) + raw s_barrier: next tile's 8 global_load_lds stay in
// flight across the barrier (T3/T4 pattern, never drain to 0 mid-loop).
// NOTE (R3 post-mortem): no min-waves launch_bounds arg — occupancy is
// LDS-bound (66KB -> 2 blocks/CU) anyway; a VGPR cap of 128 caused ~330
// dwords/thread of scratch spill (174 MB writes) and a 2.2x regression.
__global__ __launch_bounds__(256) void gemm_loss_kernel(
    const unsigned short* __restrict__ a_bf,
    const unsigned short* __restrict__ z_bf,
    float* __restrict__ partial, unsigned* __restrict__ counter,
    float* __restrict__ out) {
  __shared__ __align__(16) unsigned short Bs[2][128 * DIM];  // 64 KB
  __shared__ float red[4];
  __shared__ int lastflag;

  const int t    = threadIdx.x;
  const int bid  = blockIdx.x;
  const int rb   = bid >> 5;     // 16 row-blocks (A stripe)
  const int cg   = bid & 31;     // 32 col-groups x 8 tiles
  const int wave = t >> 6;
  const int lane = t & 63;
  const int wr   = wave >> 1, wc = wave & 1;
  const int g    = lane >> 4;
  const int r16  = lane & 15;

  // B staging source permutation (fragment order; verified R2):
  // slot it*256+wave*64+lane <- B[it*16 + r16][chunk wave*4 + (lane>>4)]
  const int src_off = r16 * DIM + (wave * 4 + (lane >> 4)) * 8;  // shorts
  const unsigned short* Bg0 = z_bf + (cg * NTILE) * 128 * DIM;

#define STAGE_B(buf, tile)                                              \
  {                                                                     \
    const unsigned short* bg = Bg0 + (tile) * 128 * DIM + src_off;      \
    _Pragma("unroll")                                                   \
    for (int it = 0; it < 8; ++it)                                      \
      gload_lds16(bg + it * 16 * DIM, (buf) + (it * 256 + wave * 64) * 8); \
  }

  STAGE_B(Bs[0], 0)

  // A fragments -> registers: af[i][ks] = A[rb*128+wr*64+i*16+r16][(ks*4+g)*8..+8]
  bf16x8 af[4][4];
  {
    const unsigned short* Arow =
        a_bf + (rb * 128 + wr * 64 + r16) * DIM + g * 8;
    #pragma unroll
    for (int i = 0; i < 4; ++i)
      #pragma unroll
      for (int ks = 0; ks < 4; ++ks)
        af[i][ks] = *(const bf16x8*)(Arow + i * 16 * DIM + ks * 32);
  }

  STAGE_B(Bs[1], 1)

  float sumt = 0.f, sumab = 0.f, logacc = 0.f, diagsum = 0.f;

  #pragma unroll
  for (int tt = 0; tt < NTILE; ++tt) {
    // wait: my 8 loads for tile tt done; tile tt+1's 8 stay in flight
    if (tt < NTILE - 1) asm volatile("s_waitcnt vmcnt(8)" ::: "memory");
    else                asm volatile("s_waitcnt vmcnt(0)" ::: "memory");
    __builtin_amdgcn_s_barrier();
    asm volatile("" ::: "memory");

    const unsigned short* Bbase = Bs[tt & 1] + wc * 8192 + lane * 8;

    f32x4 acc[4][4];
    #pragma unroll
    for (int i = 0; i < 4; ++i)
      #pragma unroll
      for (int j = 0; j < 4; ++j) acc[i][j] = 0.0f;

    #pragma unroll
    for (int ks = 0; ks < 4; ++ks) {
      bf16x8 bfr[4];
      #pragma unroll
      for (int f = 0; f < 4; ++f)
        bfr[f] = *(const bf16x8*)(Bbase + ks * 512 + f * 2048);
      #pragma unroll
      for (int i = 0; i < 4; ++i)
        #pragma unroll
        for (int j = 0; j < 4; ++j)
          acc[i][j] = __builtin_amdgcn_mfma_f32_16x16x32_bf16(
              af[i][ks], bfr[j], acc[i][j], 0, 0, 0);
    }

    // per-tile epilogue: 3 VALU + 1 trans per element, 4-way dep chains
    float st[4] = {0.f, 0.f, 0.f, 0.f};
    float sab[4] = {0.f, 0.f, 0.f, 0.f};
    float pr[4] = {1.f, 1.f, 1.f, 1.f};
    #pragma unroll
    for (int i = 0; i < 4; ++i)
      #pragma unroll
      for (int j = 0; j < 4; ++j)
        #pragma unroll
        for (int r = 0; r < 4; ++r) {
          float tv = acc[i][j][r];
          st[r]  += tv;
          sab[r] += fabsf(tv);
          pr[r] = fmaf(pr[r], __builtin_amdgcn_exp2f(-fabsf(tv)), pr[r]);
        }
    sumt  += (st[0] + st[1]) + (st[2] + st[3]);
    sumab += (sab[0] + sab[1]) + (sab[2] + sab[3]);
    // 64 factors in [1,2] -> product <= 2^64, safe; one log2 per tile
    logacc += __builtin_amdgcn_logf((pr[0] * pr[1]) * (pr[2] * pr[3]));

    // diagonal fixup (only blocks whose tiles hit the diagonal: cg in {2rb,2rb+1})
    const int ct = cg * NTILE + tt;
    if ((ct >> 4) == rb) {
      const int obase = ct * 8 + wc * 4;
      const int rbase = rb * 128 + wr * 64 + g * 4;
      float sd = 0.f;
      #pragma unroll
      for (int i = 0; i < 4; ++i)
        #pragma unroll
        for (int r = 0; r < 4; ++r) {
          int gi = rbase + i * 16 + r;
          #pragma unroll
          for (int j = 0; j < 4; ++j)
            sd += (gi == obase + j) ? acc[i][j][r] : 0.f;
        }
      diagsum += sd;
    }

    asm volatile("" ::: "memory");
    __builtin_amdgcn_s_barrier();   // all waves done reading Bs[tt&1]
    if (tt + 2 < NTILE) STAGE_B(Bs[tt & 1], tt + 2)
  }

  float local = 0.5f * (sumt + sumab) + logacc - diagsum;
  #pragma unroll
  for (int o = 32; o >= 1; o >>= 1) local += __shfl_xor(local, o);
  if (lane == 0) red[wave] = local;
  __syncthreads();

  if (t == 0) {
    float bsum = (red[0] + red[1]) + (red[2] + red[3]);
    __hip_atomic_store(&partial[bid], bsum, __ATOMIC_RELEASE,
                       __HIP_MEMORY_SCOPE_AGENT);
    unsigned prev = __hip_atomic_fetch_add(counter, 1u, __ATOMIC_ACQ_REL,
                                           __HIP_MEMORY_SCOPE_AGENT);
    lastflag = (prev == NBLK - 1);
  }
  __syncthreads();

  if (lastflag) {   // last block: deterministic fixed-order final reduction
    float s = 0.f;
    for (int i = t; i < NBLK; i += 256)
      s += __hip_atomic_load(&partial[i], __ATOMIC_RELAXED,
                             __HIP_MEMORY_SCOPE_AGENT);
    #pragma unroll
    for (int o = 32; o >= 1; o >>= 1) s += __shfl_xor(s, o);
    if (lane == 0) red[wave] = s;
    __syncthreads();
    if (t == 0)
      out[0] = ((red[0] + red[1]) + (red[2] + red[3])) * (LN2 / TOTAL_ELEMS);
  }
}

extern "C" void kernel_launch(void* const* d_in, const int* in_sizes, int n_in,
                              void* d_out, int out_size, void* d_ws, size_t ws_size,
                              hipStream_t stream) {
  const float* anchor = (const float*)d_in[0];
  const float* pos    = (const float*)d_in[1];
  const float* neg    = (const float*)d_in[2];
  char* ws = (char*)d_ws;
  unsigned short* a_bf = (unsigned short*)ws;                    // 512 KB
  unsigned short* z_bf = (unsigned short*)(ws + 524288);         // 8 MB
  float* partial       = (float*)(ws + 524288 + 8388608);        // 2 KB
  unsigned* counter    = (unsigned*)(ws + 524288 + 8388608 + 2048);

  hipMemsetAsync(counter, 0, sizeof(unsigned), stream);
  norm_kernel<<<dim3(NROWS / 8), dim3(256), 0, stream>>>(
      anchor, pos, neg, a_bf, z_bf);
  gemm_loss_kernel<<<dim3(NBLK), dim3(256), 0, stream>>>(
      a_bf, z_bf, partial, counter, (float*)d_out);
}

// Round 5
// 54.711 us; speedup vs baseline: 1.9574x; 1.6484x over previous
//
#include <hip/hip_runtime.h>
#include <stdint.h>

// Problem constants
#define N_ANCHOR 2048
#define DIM 128
#define NEG_PER 15
#define NZ 32768                    // 2048*16 candidate rows
#define NROWS (N_ANCHOR + NZ)       // 34816
#define INV_TEMP 3.3333333333333335f
#define LOG2E 1.4426950408889634f
#define LN2 0.6931471805599453f
#define TOTAL_ELEMS 67108864.0f
#define A_PRESCALE (INV_TEMP * LOG2E)   // folded into anchor normalization

#define BM 256                      // rows per block (4 waves x 64)
#define CPB 512                     // cols per block
#define NT (CPB / 32)               // 16 B-tiles of 32 cols
#define RB (N_ANCHOR / BM)          // 8
#define CG (NZ / CPB)               // 64
#define NBLK (RB * CG)              // 512

using bf16x8 = __attribute__((ext_vector_type(8))) __bf16;
using f32x4  = __attribute__((ext_vector_type(4))) float;

// ---------- helpers ----------
static __device__ __forceinline__ unsigned short f2bf(float f) {
  union { float f; unsigned u; } v; v.f = f;
  unsigned r = v.u + 0x7FFF + ((v.u >> 16) & 1);   // round-to-nearest-even
  return (unsigned short)(r >> 16);
}

static __device__ __forceinline__ void gload_lds16(const void* g, void* l) {
  __builtin_amdgcn_global_load_lds(
      (const __attribute__((address_space(1))) void*)g,
      (__attribute__((address_space(3))) void*)l, 16, 0, 0);
}

// ---------- kernel 1: L2-normalize rows, cast to bf16 ----------
__global__ __launch_bounds__(256) void norm_kernel(
    const float* __restrict__ anchor, const float* __restrict__ pos,
    const float* __restrict__ neg, unsigned short* __restrict__ a_bf,
    unsigned short* __restrict__ z_bf) {
  int row = blockIdx.x * 8 + (threadIdx.x >> 5);
  int l32 = threadIdx.x & 31;
  const float* src;
  unsigned short* dst;
  float pre;
  if (row < N_ANCHOR) {
    src = anchor + row * DIM;
    dst = a_bf + row * DIM;
    pre = A_PRESCALE;
  } else {
    int rz = row - N_ANCHOR;
    int j = rz >> 4, k = rz & 15;
    src = (k == 0) ? (pos + j * DIM) : (neg + (j * NEG_PER + (k - 1)) * DIM);
    dst = z_bf + rz * DIM;
    pre = 1.0f;
  }
  float4 v = ((const float4*)src)[l32];
  float s = v.x * v.x + v.y * v.y + v.z * v.z + v.w * v.w;
  #pragma unroll
  for (int o = 16; o >= 1; o >>= 1) s += __shfl_xor(s, o, 32);
  float scale = pre / fmaxf(sqrtf(s), 1e-12f);
  ushort4 o4;
  o4.x = f2bf(v.x * scale); o4.y = f2bf(v.y * scale);
  o4.z = f2bf(v.z * scale); o4.w = f2bf(v.w * scale);
  ((ushort4*)dst)[l32] = o4;
}

// ---------- kernel 2: fused GEMM + loss ----------
// A stripe 256x128 in REGISTERS (af[4][4], 64 VGPR/lane, loaded once, L2-hot).
// B: 32-col tiles, fragment order, double-buffered 2x8KB LDS.
// Counted vmcnt(2): next tile's 2 global_load_lds stay in flight across the
// barrier. lgkmcnt(0) before end barrier: no wave crosses with a ds_read of
// the soon-to-be-overwritten buffer still outstanding.
// Tile loop NOT unrolled (R4 post-mortem: unrolled loop + wide acc => spills).
__global__ __launch_bounds__(256) void gemm_loss_kernel(
    const unsigned short* __restrict__ a_bf,
    const unsigned short* __restrict__ z_bf,
    float* __restrict__ partial, unsigned* __restrict__ counter,
    float* __restrict__ out) {
  __shared__ __align__(16) unsigned short Bs[2][512 * 8];   // 2 x 8 KB
  __shared__ float red[4];
  __shared__ int lastflag;

  const int t    = threadIdx.x;
  const int bid  = blockIdx.x;
  const int rb   = bid / CG;
  const int cgi  = bid % CG;
  const int wave = t >> 6;
  const int lane = t & 63;
  const int g    = lane >> 4;
  const int r16  = lane & 15;
  const int c0   = cgi * CPB;

  // B stage source pointers (fragment order): LDS slot s = it*256 + t holds
  // B[col j*16+rr][kchunk ks*4+gg] with j=s>>8, ks=(s>>6)&3, gg=(s>>4)&3, rr=s&15
  const unsigned short* pB[2];
  #pragma unroll
  for (int it = 0; it < 2; ++it) {
    int s = it * 256 + t;
    int j = s >> 8, ks = (s >> 6) & 3, gg = (s >> 4) & 3, rr = s & 15;
    pB[it] = z_bf + (size_t)(c0 + j * 16 + rr) * DIM + (ks * 4 + gg) * 8;
  }

#define STAGE_B(buf, tt)                                              \
  {                                                                   \
    gload_lds16(pB[0] + (tt) * 32 * DIM, (buf) + (wave * 64) * 8);    \
    gload_lds16(pB[1] + (tt) * 32 * DIM, (buf) + (256 + wave * 64) * 8); \
  }

  STAGE_B(Bs[0], 0)

  // A fragments: af[i][ks] = A[rb*256 + wave*64 + i*16 + r16][(ks*4+g)*8 ..+8]
  bf16x8 af[4][4];
  {
    const unsigned short* Ar =
        a_bf + (size_t)(rb * BM + wave * 64 + r16) * DIM + g * 8;
    #pragma unroll
    for (int i = 0; i < 4; ++i)
      #pragma unroll
      for (int ks = 0; ks < 4; ++ks)
        af[i][ks] = *(const bf16x8*)(Ar + i * 16 * DIM + ks * 32);
  }

  float sumt = 0.f, sumab = 0.f, logacc = 0.f, diagsum = 0.f;
  const bool diagblk = (cgi >> 3) == rb;   // this block touches the diagonal
  const int cbase = c0 >> 4;               // owner-anchor base of col range
  const int rbase = rb * BM + wave * 64 + g * 4;

  #pragma unroll 1
  for (int tt = 0; tt < NT; ++tt) {
    if (tt + 1 < NT) {
      STAGE_B(Bs[(tt + 1) & 1], tt + 1)
      asm volatile("s_waitcnt vmcnt(2)" ::: "memory");
    } else {
      asm volatile("s_waitcnt vmcnt(0)" ::: "memory");
    }
    __builtin_amdgcn_s_barrier();
    asm volatile("" ::: "memory");

    const unsigned short* Bb = Bs[tt & 1];

    f32x4 acc[4][2];
    #pragma unroll
    for (int i = 0; i < 4; ++i) { acc[i][0] = 0.f; acc[i][1] = 0.f; }

    #pragma unroll
    for (int ks = 0; ks < 4; ++ks) {
      bf16x8 b0 = *(const bf16x8*)(Bb + (ks * 64 + lane) * 8);
      bf16x8 b1 = *(const bf16x8*)(Bb + ((4 + ks) * 64 + lane) * 8);
      #pragma unroll
      for (int i = 0; i < 4; ++i) {
        acc[i][0] = __builtin_amdgcn_mfma_f32_16x16x32_bf16(af[i][ks], b0,
                                                            acc[i][0], 0, 0, 0);
        acc[i][1] = __builtin_amdgcn_mfma_f32_16x16x32_bf16(af[i][ks], b1,
                                                            acc[i][1], 0, 0, 0);
      }
    }

    // epilogue: 3 VALU + 1 trans per element (t-units; *LN2 at the end)
    float st[4]  = {0.f, 0.f, 0.f, 0.f};
    float sab[4] = {0.f, 0.f, 0.f, 0.f};
    float pr[4]  = {1.f, 1.f, 1.f, 1.f};
    #pragma unroll
    for (int i = 0; i < 4; ++i)
      #pragma unroll
      for (int j = 0; j < 2; ++j)
        #pragma unroll
        for (int r = 0; r < 4; ++r) {
          float tv = acc[i][j][r];
          st[r]  += tv;
          sab[r] += fabsf(tv);
          pr[r] = fmaf(pr[r], __builtin_amdgcn_exp2f(-fabsf(tv)), pr[r]);
        }
    sumt  += (st[0] + st[1]) + (st[2] + st[3]);
    sumab += (sab[0] + sab[1]) + (sab[2] + sab[3]);
    // 8 factors in [1,2] per pr => product <= 2^32: safe; log2 via amdgcn_logf
    logacc += __builtin_amdgcn_logf((pr[0] * pr[1]) * (pr[2] * pr[3]));

    if (diagblk) {
      #pragma unroll
      for (int j = 0; j < 2; ++j) {
        int o = cbase + tt * 2 + j;          // owner anchor of col group j
        #pragma unroll
        for (int i = 0; i < 4; ++i)
          #pragma unroll
          for (int r = 0; r < 4; ++r)
            diagsum += (rbase + i * 16 + r == o) ? acc[i][j][r] : 0.f;
      }
    }

    asm volatile("s_waitcnt lgkmcnt(0)" ::: "memory");
    __builtin_amdgcn_s_barrier();
    asm volatile("" ::: "memory");
  }

  float local = 0.5f * (sumt + sumab) + logacc - diagsum;
  #pragma unroll
  for (int o = 32; o >= 1; o >>= 1) local += __shfl_xor(local, o);
  if (lane == 0) red[wave] = local;
  __syncthreads();

  if (t == 0) {
    float bsum = (red[0] + red[1]) + (red[2] + red[3]);
    __hip_atomic_store(&partial[bid], bsum, __ATOMIC_RELEASE,
                       __HIP_MEMORY_SCOPE_AGENT);
    unsigned prev = __hip_atomic_fetch_add(counter, 1u, __ATOMIC_ACQ_REL,
                                           __HIP_MEMORY_SCOPE_AGENT);
    lastflag = (prev == NBLK - 1);
  }
  __syncthreads();

  if (lastflag) {   // last block: deterministic fixed-order final reduction
    float s = 0.f;
    for (int i = t; i < NBLK; i += 256)
      s += __hip_atomic_load(&partial[i], __ATOMIC_RELAXED,
                             __HIP_MEMORY_SCOPE_AGENT);
    #pragma unroll
    for (int o = 32; o >= 1; o >>= 1) s += __shfl_xor(s, o);
    if (lane == 0) red[wave] = s;
    __syncthreads();
    if (t == 0)
      out[0] = ((red[0] + red[1]) + (red[2] + red[3])) * (LN2 / TOTAL_ELEMS);
  }
}

extern "C" void kernel_launch(void* const* d_in, const int* in_sizes, int n_in,
                              void* d_out, int out_size, void* d_ws, size_t ws_size,
                              hipStream_t stream) {
  const float* anchor = (const float*)d_in[0];
  const float* pos    = (const float*)d_in[1];
  const float* neg    = (const float*)d_in[2];
  char* ws = (char*)d_ws;
  unsigned short* a_bf = (unsigned short*)ws;                    // 512 KB
  unsigned short* z_bf = (unsigned short*)(ws + 524288);         // 8 MB
  float* partial       = (float*)(ws + 524288 + 8388608);        // 2 KB
  unsigned* counter    = (unsigned*)(ws + 524288 + 8388608 + 4096);

  hipMemsetAsync(counter, 0, sizeof(unsigned), stream);
  norm_kernel<<<dim3(NROWS / 8), dim3(256), 0, stream>>>(
      anchor, pos, neg, a_bf, z_bf);
  gemm_loss_kernel<<<dim3(NBLK), dim3(256), 0, stream>>>(
      a_bf, z_bf, partial, counter, (float*)d_out);
}